// Round 1
// baseline (1162.899 us; speedup 1.0000x reference)
//
#include <hip/hip_runtime.h>

// Problem constants (fixed by the reference setup_inputs).
constexpr int B_ = 1024;
constexpr int S_ = 200;
constexpr int Q_ = 512;
constexpr int TQ = 2 * Q_;              // 1024 floats per batch row
constexpr int ROWS = B_ * (S_ - 1);     // 203,776 (b, t=i+1) rows to scan

constexpr int BLOCK = 256;              // 4 waves/block
constexpr int GRID  = 2048;
constexpr int WAVES = GRID * (BLOCK / 64);   // 8192 waves = 32/CU (full occupancy)

// One wave per batch row. The row is one-hot: exactly one nonzero among 1024
// floats; 60% of the time it's in the first half (correct answers).
// Scan in 512-byte chunks (64 lanes x float2, coalesced) with a wave-uniform
// ballot early-exit after each chunk. Expected traffic:
//   512B * [(1+2+3+4)*0.15 + (5+6+7+8)*0.10] = 2.05 KB/row   (was 2.8 KB/row)
// Latency chain: ~25 rows/wave * 4.1 round-trips * ~375ns ~= 38us per wave,
// below the ~68us BW floor at 6.3 TB/s -> still bandwidth-bound.
__global__ __launch_bounds__(BLOCK, 8) void lossFunc_kernel(
    const float* __restrict__ pred,    // [B, S, Q]
    const float* __restrict__ batch,   // [B, S, 2Q]
    float* __restrict__ out)           // [1], pre-zeroed
{
    const int lane = threadIdx.x & 63;
    const int wid  = threadIdx.x >> 6;
    const int gw   = blockIdx.x * (BLOCK / 64) + wid;

    float acc = 0.0f;

    for (int r = gw; r < ROWS; r += WAVES) {
        const int b = r / (S_ - 1);
        const int i = r - b * (S_ - 1);   // 0 .. S-2; batch step t = i+1

        const float2* row =
            (const float2*)(batch + ((size_t)b * S_ + (i + 1)) * TQ);

        int j = -1;
        #pragma unroll
        for (int c = 0; c < 8; ++c) {
            // Chunk c covers floats [c*128, c*128+128) = 512 B, coalesced.
            const float2 v = row[(c << 6) + lane];
            const int e = (c << 7) + (lane << 1);
            if (v.x != 0.0f) j = e;
            if (v.y != 0.0f) j = e + 1;
            // Wave-uniform early exit: someone found the one-hot.
            if (__ballot(j >= 0) != 0ULL) break;
        }

        // Exactly one lane holds the nonzero.
        if (j >= 0) {
            const bool corr = (j < Q_);
            const int  q    = corr ? j : (j - Q_);
            const float p   = pred[((size_t)b * S_ + i) * Q_ + q];
            if (p > 0.0f) {
                acc -= corr ? __logf(p) : __logf(1.0f - p);
            }
        }
    }

    // Wave reduction (64 lanes).
    #pragma unroll
    for (int off = 32; off > 0; off >>= 1)
        acc += __shfl_down(acc, off, 64);

    __shared__ float waveSums[BLOCK / 64];
    if (lane == 0) waveSums[wid] = acc;
    __syncthreads();

    if (threadIdx.x == 0) {
        float s = 0.0f;
        #pragma unroll
        for (int w = 0; w < BLOCK / 64; ++w) s += waveSums[w];
        atomicAdd(out, s);
    }
}

extern "C" void kernel_launch(void* const* d_in, const int* in_sizes, int n_in,
                              void* d_out, int out_size, void* d_ws, size_t ws_size,
                              hipStream_t stream) {
    const float* pred  = (const float*)d_in[0];
    const float* batch = (const float*)d_in[1];
    float* out = (float*)d_out;

    // Harness poisons d_out to 0xAA before each call — zero it (capture-safe).
    hipMemsetAsync(out, 0, sizeof(float), stream);

    lossFunc_kernel<<<GRID, BLOCK, 0, stream>>>(pred, batch, out);
}